// Round 5
// baseline (116.709 us; speedup 1.0000x reference)
//
#include <hip/hip_runtime.h>
#include <hip/hip_bf16.h>
#include <stdint.h>

typedef __bf16 bf16;
typedef __bf16 bf16x8 __attribute__((ext_vector_type(8)));
typedef __bf16 bf16x4 __attribute__((ext_vector_type(4)));
typedef float f32x4 __attribute__((ext_vector_type(4)));

#define KDIM 768
#define NHEAD 12
#define HDIM 64
#define NTOK 1024
#define BATCH 8

// XOR swizzle for row-major [row][128B-row] LDS tiles: 16B chunk -> distinct bank-quad
#define SWZ(row, b) ((b) ^ (((row) & 7) << 4))

__device__ __forceinline__ void gl_lds16(const bf16* g, bf16* l) {
    __builtin_amdgcn_global_load_lds((const __attribute__((address_space(1))) void*)g,
                                     (__attribute__((address_space(3))) void*)l, 16, 0, 0);
}

// ---------------- fp32 -> bf16 convert (all three tensors, one launch) ----------------
__global__ void k_cvt_all(const float* __restrict__ x, const float* __restrict__ wq,
                          const float* __restrict__ wp, bf16* __restrict__ xb,
                          bf16* __restrict__ wqb, bf16* __restrict__ wpb) {
    int b = blockIdx.x;
    const float* src;
    bf16* dst;
    int base;
    if (b < 6144)       { src = x;  dst = xb;  base = b; }
    else if (b < 7872)  { src = wq; dst = wqb; base = b - 6144; }
    else                { src = wp; dst = wpb; base = b - 7872; }
    int i = (base * 256 + threadIdx.x) * 4;
    float4 v = *(const float4*)(src + i);
    bf16x4 o;
    o[0] = (bf16)v.x; o[1] = (bf16)v.y; o[2] = (bf16)v.z; o[3] = (bf16)v.w;
    *(bf16x4*)(dst + i) = o;
}

// =====================================================================================
// GEMM: 128(M) x 256(N) x K tiles, BK=64, 8 waves (2M x 4N), per-wave 64x64 output.
// LDS: 3-slot ring (A 16KB + B 32KB per slot = 144 KB): iteration kt computes slot
// kt%3 while staging kt+2 -> 2-iteration prefetch lead; counted vmcnt(6) per iteration
// (drains only tile kt+1's 6 loads; never the just-issued ones). Zero bank conflicts
// via XOR swizzle with pre-swizzled global source (global_load_lds writes lane-linear).
// LDS row = 128B = one tile-row's K=64 bf16; chunk (R,c) holds global k-chunk c^(R&7).
// =====================================================================================

#define G_MFMA(a, b, c) __builtin_amdgcn_mfma_f32_16x16x32_bf16(a, b, c, 0, 0, 0)

// frag reads: row R -> byte R*128 + ((kc*64 + lg*16) ^ ((lr&7)<<4))  (R&7 == lr&7)
#define LOADA(SC)                                                              \
    _Pragma("unroll")                                                          \
    for (int m = 0; m < 4; ++m) {                                              \
        const char* rp = (const char*)sA[SC] + (wr * 64 + m * 16 + lr) * 128;  \
        af[m][0] = *(const bf16x8*)(rp + k0off);                               \
        af[m][1] = *(const bf16x8*)(rp + k1off);                               \
    }

#define LOADB(SC, n0, bfr)                                                     \
    _Pragma("unroll")                                                          \
    for (int nn = 0; nn < 2; ++nn) {                                           \
        const char* rp = (const char*)sB[SC] + (wc * 64 + ((n0) + nn) * 16 + lr) * 128; \
        bfr[nn][0] = *(const bf16x8*)(rp + k0off);                             \
        bfr[nn][1] = *(const bf16x8*)(rp + k1off);                             \
    }

#define MMQ(ch, bfr)                                                           \
    __builtin_amdgcn_s_setprio(1);                                             \
    _Pragma("unroll")                                                          \
    for (int m = 0; m < 4; ++m)                                                \
        _Pragma("unroll")                                                      \
        for (int nn = 0; nn < 2; ++nn) {                                       \
            acc[m][2 * (ch) + nn] = G_MFMA(af[m][0], bfr[nn][0], acc[m][2 * (ch) + nn]); \
            acc[m][2 * (ch) + nn] = G_MFMA(af[m][1], bfr[nn][1], acc[m][2 * (ch) + nn]); \
        }                                                                      \
    __builtin_amdgcn_s_setprio(0);

// one K-tile iteration: compute slot SC, stage tile kt+2 into slot SS
#define ITER(SC, SS, kt) do {                                                  \
    bf16x8 af[4][2];                                                           \
    LOADA(SC);                                                                 \
    bf16x8 b0[2][2];                                                           \
    LOADB(SC, 0, b0);                                                          \
    if ((kt) + 2 < NKT) {                                                      \
        const bf16* As_ = Ab + (size_t)Rt * KDIM + ((kt) + 2) * 64 + wp8;      \
        gl_lds16(As_,            &sA[SS][t * 8]);                              \
        gl_lds16(As_ + 64 * KDIM, &sA[SS][t * 8 + 4096]);                      \
        const bf16* Bs_ = Wb + (size_t)Rt * KDIM + ((kt) + 2) * 64 + wp8;      \
        gl_lds16(Bs_,            &sB[SS][t * 8]);                              \
        gl_lds16(Bs_ + 64 * KDIM, &sB[SS][t * 8 + 4096]);                      \
    }                                                                          \
    MMQ(0, b0);                                                                \
    asm volatile("s_barrier" ::: "memory");                                    \
    bf16x8 b1[2][2];                                                           \
    LOADB(SC, 2, b1);                                                          \
    if ((kt) + 2 < NKT) {                                                      \
        const bf16* Bs_ = Wb + (size_t)Rt * KDIM + ((kt) + 2) * 64 + wp8;      \
        gl_lds16(Bs_ + 128 * KDIM, &sB[SS][t * 8 + 8192]);                     \
        gl_lds16(Bs_ + 192 * KDIM, &sB[SS][t * 8 + 12288]);                    \
    }                                                                          \
    MMQ(1, b1);                                                                \
    if ((kt) <= NKT - 3)      { asm volatile("s_waitcnt vmcnt(6)" ::: "memory"); } \
    else if ((kt) == NKT - 2) { asm volatile("s_waitcnt vmcnt(0)" ::: "memory"); } \
    asm volatile("s_barrier" ::: "memory");                                    \
} while (0)

#define NKT 12  // K / 64

#define GEMM_BODY(A_PTR, W_PTR)                                                \
    const int t = threadIdx.x;                                                 \
    const int lane = t & 63;                                                   \
    const int wv = t >> 6;                   /* 0..7 */                        \
    const int wr = wv >> 2, wc = wv & 3;     /* 2 x 4 */                       \
    const int lr = lane & 15, lg = lane >> 4;                                  \
    const int xorb = (lr & 7) << 4;                                            \
    const int k0off = (lg * 16) ^ xorb;                                        \
    const int k1off = (64 + lg * 16) ^ xorb;                                   \
    const int Rt = t >> 3;                   /* staged row 0..63 */            \
    const int wp8 = ((t & 7) ^ (Rt & 7)) * 8; /* pre-swizzled src k-offset */  \
    const int bm = blockIdx.x, bn = blockIdx.y;                                \
    const bf16* Ab = (A_PTR) + (size_t)bm * 128 * KDIM;                        \
    const bf16* Wb = (W_PTR) + (size_t)bn * 256 * KDIM;                        \
    f32x4 acc[4][4] = {};                                                      \
    /* prologue: stage tiles 0,1 into slots 0,1 (12 loads) */                  \
    {                                                                          \
        const bf16* As_ = Ab + (size_t)Rt * KDIM + wp8;                        \
        const bf16* Bs_ = Wb + (size_t)Rt * KDIM + wp8;                        \
        gl_lds16(As_,             &sA[0][t * 8]);                              \
        gl_lds16(As_ + 64 * KDIM, &sA[0][t * 8 + 4096]);                       \
        gl_lds16(Bs_,             &sB[0][t * 8]);                              \
        gl_lds16(Bs_ + 64 * KDIM, &sB[0][t * 8 + 4096]);                       \
        gl_lds16(Bs_ + 128 * KDIM, &sB[0][t * 8 + 8192]);                      \
        gl_lds16(Bs_ + 192 * KDIM, &sB[0][t * 8 + 12288]);                     \
        gl_lds16(As_ + 64,             &sA[1][t * 8]);                         \
        gl_lds16(As_ + 64 + 64 * KDIM, &sA[1][t * 8 + 4096]);                  \
        gl_lds16(Bs_ + 64,             &sB[1][t * 8]);                         \
        gl_lds16(Bs_ + 64 + 64 * KDIM, &sB[1][t * 8 + 4096]);                  \
        gl_lds16(Bs_ + 64 + 128 * KDIM, &sB[1][t * 8 + 8192]);                 \
        gl_lds16(Bs_ + 64 + 192 * KDIM, &sB[1][t * 8 + 12288]);                \
    }                                                                          \
    asm volatile("s_waitcnt vmcnt(6)" ::: "memory");                           \
    asm volatile("s_barrier" ::: "memory");                                    \
    _Pragma("unroll 1")                                                        \
    for (int g = 0; g < 4; ++g) {                                              \
        int kt = g * 3;                                                        \
        ITER(0, 2, kt);                                                        \
        ITER(1, 0, kt + 1);                                                    \
        ITER(2, 1, kt + 2);                                                    \
    }

__global__ __launch_bounds__(512) void k_gemm_qkv(
    const bf16* __restrict__ A, const bf16* __restrict__ W,
    bf16* __restrict__ qb, bf16* __restrict__ kb, bf16* __restrict__ vb)
{
    __shared__ __attribute__((aligned(16))) bf16 sA[3][8192];   // 128 x 64 per slot
    __shared__ __attribute__((aligned(16))) bf16 sB[3][16384];  // 256 x 64 per slot
    GEMM_BODY(A, W);

    const float QSC = 0.18033688011112042f;  // 0.125 * log2(e) folded into q
#pragma unroll
    for (int n = 0; n < 4; ++n) {
        int o = bn * 256 + wc * 64 + n * 16 + lr;
        int s = o / 768;
        int rem = o - s * 768;
        int head = rem >> 6;
        int d = o & 63;
        bf16* dst = (s == 0) ? qb : ((s == 1) ? kb : vb);
        float sc = (s == 0) ? QSC : 1.0f;
#pragma unroll
        for (int m = 0; m < 4; ++m) {
            int grow = bm * 128 + wr * 64 + m * 16 + lg * 4;
            int bidx = grow >> 10;
            int tok = grow & 1023;
            size_t base = (((size_t)bidx * NHEAD + head) * NTOK + tok) * HDIM + d;
#pragma unroll
            for (int r = 0; r < 4; ++r)
                dst[base + (size_t)r * HDIM] = (bf16)(acc[m][n][r] * sc);
        }
    }
}

__global__ __launch_bounds__(512) void k_gemm_proj(
    const bf16* __restrict__ A, const bf16* __restrict__ W,
    const float* __restrict__ bias, float* __restrict__ out)
{
    __shared__ __attribute__((aligned(16))) bf16 sA[3][8192];
    __shared__ __attribute__((aligned(16))) bf16 sB[3][16384];
    GEMM_BODY(A, W);

#pragma unroll
    for (int n = 0; n < 4; ++n) {
        int col = bn * 256 + wc * 64 + n * 16 + lr;
        float bv = bias[col];
#pragma unroll
        for (int m = 0; m < 4; ++m) {
            int grow = bm * 128 + wr * 64 + m * 16 + lg * 4;
#pragma unroll
            for (int r = 0; r < 4; ++r)
                out[(size_t)(grow + r) * KDIM + col] = acc[m][n][r] + bv;
        }
    }
}

// ---------------- banded flash attention ----------------
// grid: 1536 blocks XCD-swizzled. 4 waves x 16 q-rows; visible key tiles j in
// {wv-1,wv,wv+1}. K/V LDS double-buffered -> ONE barrier per kh; next kh's K/V
// reg-prefetched (vmcnt never drained in-loop by the barrier path).
__global__ __launch_bounds__(256) void k_attn(
    const bf16* __restrict__ qbuf, const bf16* __restrict__ kbuf,
    const bf16* __restrict__ vbuf, bf16* __restrict__ ob)
{
    const int x = blockIdx.x;
    const int sub = x >> 3;
    const int bh = (x & 7) * 12 + (sub >> 4);   // 12 bh per XCD
    const int qblk = sub & 15;                   // == h_q
    const int head = bh % NHEAD, bidx = bh / NHEAD;
    const bf16* Q  = qbuf + (size_t)bh * NTOK * HDIM;
    const bf16* Kp = kbuf + (size_t)bh * NTOK * HDIM;
    const bf16* Vp = vbuf + (size_t)bh * NTOK * HDIM;

    const int t = threadIdx.x, lane = t & 63, wv = t >> 6;
    const int lr = lane & 15, lg = lane >> 4, lkb = lg * 8;

    __shared__ bf16 Ks[2][64 * 64];   // [key][d], swizzled
    __shared__ bf16 vT[2][64 * 64];   // [d][key], swizzled
    __shared__ bf16 pls[4][16 * 64];  // per-wave P [q][key], swizzled

    // zero own wave's P tile once (invisible key tiles are never written)
    {
        bf16x8 z = {};
        *(bf16x8*)&pls[wv][lane * 16] = z;
        *(bf16x8*)&pls[wv][lane * 16 + 8] = z;
    }

    bf16x8 qf[2];
#pragma unroll
    for (int ks = 0; ks < 2; ++ks)
        qf[ks] = *(const bf16x8*)(Q + (size_t)(qblk * 64 + wv * 16 + lr) * HDIM + ks * 32 + lkb);

    f32x4 acc[4] = {};
    float mrow[4] = {-1e30f, -1e30f, -1e30f, -1e30f};
    float lrow[4] = {0.f, 0.f, 0.f, 0.f};

    const int kh0 = (qblk - 3 < 0) ? 0 : qblk - 3;
    const int kh1 = (qblk + 3 > 15) ? 15 : qblk + 3;

    const int sj = t >> 2;           // staged key 0..63
    const int sd = (t & 3) * 16;     // staged d elt 0,16,32,48

    const bf16* ks0 = Kp + (size_t)(kh0 * 64 + sj) * HDIM + sd;
    const bf16* vs0 = Vp + (size_t)(kh0 * 64 + sj) * HDIM + sd;
    bf16x8 gk0 = *(const bf16x8*)ks0, gk1 = *(const bf16x8*)(ks0 + 8);
    bf16x8 gv0 = *(const bf16x8*)vs0, gv1 = *(const bf16x8*)(vs0 + 8);

    char* pb8 = (char*)pls[wv];
    const int wq0 = wv * 16 + lg * 4;
    int cur = 0;

    for (int kh = kh0; kh <= kh1; ++kh) {
        char* kb8 = (char*)Ks[cur];
        char* vb8 = (char*)vT[cur];
        // stage K (row-major, swizzled) into buf[cur] (nobody reads it: they read cur^1)
        {
            int kbo = sj * 128 + sd * 2;
            *(bf16x8*)(kb8 + SWZ(sj, kbo)) = gk0;
            *(bf16x8*)(kb8 + SWZ(sj, kbo + 16)) = gk1;
        }
#pragma unroll
        for (int ii = 0; ii < 8; ++ii) {
            int d = sd + ii;
            *(bf16*)(vb8 + SWZ(d, (d << 7) + (sj << 1))) = gv0[ii];
        }
#pragma unroll
        for (int ii = 0; ii < 8; ++ii) {
            int d = sd + 8 + ii;
            *(bf16*)(vb8 + SWZ(d, (d << 7) + (sj << 1))) = gv1[ii];
        }
        // prefetch next kh's K/V (in flight across the barrier)
        if (kh < kh1) {
            const bf16* kn = Kp + (size_t)((kh + 1) * 64 + sj) * HDIM + sd;
            const bf16* vn = Vp + (size_t)((kh + 1) * 64 + sj) * HDIM + sd;
            gk0 = *(const bf16x8*)kn; gk1 = *(const bf16x8*)(kn + 8);
            gv0 = *(const bf16x8*)vn; gv1 = *(const bf16x8*)(vn + 8);
        }
        asm volatile("s_waitcnt lgkmcnt(0)" ::: "memory");
        __builtin_amdgcn_s_barrier();

        // ---- QK^T over visible key tiles ----
        f32x4 s[3];
#pragma unroll
        for (int jj = 0; jj < 3; ++jj) {
            int j = wv - 1 + jj;
            if (j >= 0 && j <= 3) {        // wave-uniform
                int key = j * 16 + lr;
                int kbase = key * 128;
                bf16x8 kf0 = *(const bf16x8*)(kb8 + SWZ(key, kbase + lg * 16));
                bf16x8 kf1 = *(const bf16x8*)(kb8 + SWZ(key, kbase + 64 + lg * 16));
                f32x4 sv = {};
                sv = __builtin_amdgcn_mfma_f32_16x16x32_bf16(qf[0], kf0, sv, 0, 0, 0);
                sv = __builtin_amdgcn_mfma_f32_16x16x32_bf16(qf[1], kf1, sv, 0, 0, 0);
#pragma unroll
                for (int r = 0; r < 4; ++r) {
                    int dw = wq0 + r - key;
                    sv[r] = (dw >= -5 && dw <= 5) ? sv[r] : -1e30f;
                }
                s[jj] = sv;
            } else {
                s[jj] = f32x4{-1e30f, -1e30f, -1e30f, -1e30f};
            }
        }

        // ---- online softmax, once per kh ----
        float pm[4], scl[4];
#pragma unroll
        for (int r = 0; r < 4; ++r) pm[r] = fmaxf(fmaxf(s[0][r], s[1][r]), s[2][r]);
#pragma unroll
        for (int off = 1; off < 16; off <<= 1)
#pragma unroll
            for (int r = 0; r < 4; ++r) pm[r] = fmaxf(pm[r], __shfl_xor(pm[r], off));
#pragma unroll
        for (int r = 0; r < 4; ++r) {
            float mn = fmaxf(mrow[r], pm[r]);
            scl[r] = exp2f(mrow[r] - mn);
            mrow[r] = mn;
        }
#pragma unroll
        for (int dt = 0; dt < 4; ++dt)
#pragma unroll
            for (int r = 0; r < 4; ++r) acc[dt][r] *= scl[r];

        // ---- P = exp2(s - m) -> bf16 -> per-wave LDS tile ----
        float psum[4] = {0.f, 0.f, 0.f, 0.f};
#pragma unroll
        for (int jj = 0; jj < 3; ++jj) {
            int j = wv - 1 + jj;
            if (j >= 0 && j <= 3) {
#pragma unroll
                for (int r = 0; r < 4; ++r) {
                    float p = exp2f(s[jj][r] - mrow[r]);
                    psum[r] += p;
                    int row = lg * 4 + r;
                    *(bf16*)(pb8 + SWZ(row, row * 128 + (j * 16 + lr) * 2)) = (bf16)p;
                }
            }
        }
#pragma unroll
        for (int r = 0; r < 4; ++r) lrow[r] = lrow[r] * scl[r] + psum[r];

        // ---- PV: A = P[16x64], B = V^T ----
        bf16x8 pf0 = *(const bf16x8*)(pb8 + SWZ(lr, lr * 128 + lg * 16));
        bf16x8 pf1 = *(const bf16x8*)(pb8 + SWZ(lr, lr * 128 + 64 + lg * 16));
#pragma unroll
        for (int dt = 0; dt < 4; ++dt) {
            int vrow = dt * 16 + lr;
            bf16x8 vf0 = *(const bf16x8*)(vb8 + SWZ(vrow, vrow * 128 + lg * 16));
            bf16x8 vf1 = *(const bf16x8*)(vb8 + SWZ(vrow, vrow * 128 + 64 + lg * 16));
            acc[dt] = __builtin_amdgcn_mfma_f32_16x16x32_bf16(pf0, vf0, acc[dt], 0, 0, 0);
            acc[dt] = __builtin_amdgcn_mfma_f32_16x16x32_bf16(pf1, vf1, acc[dt], 0, 0, 0);
        }
        cur ^= 1;
    } // kh

    // ---- finalize ----
#pragma unroll
    for (int off = 1; off < 16; off <<= 1)
#pragma unroll
        for (int r = 0; r < 4; ++r) lrow[r] += __shfl_xor(lrow[r], off);

#pragma unroll
    for (int r = 0; r < 4; ++r) {
        float inv = 1.0f / lrow[r];
        int tok = qblk * 64 + wv * 16 + lg * 4 + r;
        size_t rowbase = ((size_t)bidx * NTOK + tok) * KDIM + head * HDIM;
#pragma unroll
        for (int dt = 0; dt < 4; ++dt)
            ob[rowbase + dt * 16 + lr] = (bf16)(acc[dt][r] * inv);
    }
}

// ---------------- launcher ----------------
extern "C" void kernel_launch(void* const* d_in, const int* in_sizes, int n_in,
                              void* d_out, int out_size, void* d_ws, size_t ws_size,
                              hipStream_t stream) {
    const float* x      = (const float*)d_in[0];
    const float* w_qkv  = (const float*)d_in[1];
    const float* w_proj = (const float*)d_in[2];
    const float* b_proj = (const float*)d_in[3];
    float* out = (float*)d_out;

    char* ws = (char*)d_ws;
    bf16* xb  = (bf16*)(ws);                  // 8192*768*2   = 12582912
    bf16* wqb = (bf16*)(ws + 12582912);       // 2304*768*2   =  3538944
    bf16* wpb = (bf16*)(ws + 16121856);       // 768*768*2    =  1179648
    bf16* qb  = (bf16*)(ws + 17301504);       // 96*1024*64*2 = 12582912
    bf16* kb  = (bf16*)(ws + 29884416);
    bf16* vb  = (bf16*)(ws + 42467328);
    bf16* aob = (bf16*)(ws + 55050240);       // attn out bf16 [8192][768]

    hipLaunchKernelGGL(k_cvt_all, dim3(8448), dim3(256), 0, stream, x, w_qkv, w_proj, xb, wqb, wpb);
    hipLaunchKernelGGL(k_gemm_qkv, dim3(64, 9), dim3(512), 0, stream, xb, wqb, qb, kb, vb);
    hipLaunchKernelGGL(k_attn,     dim3(1536), dim3(256), 0, stream, qb, kb, vb, aob);
    hipLaunchKernelGGL(k_gemm_proj, dim3(64, 3), dim3(512), 0, stream, aob, wpb, b_proj, out);
}

// Round 6
// 111.517 us; speedup vs baseline: 1.0466x; 1.0466x over previous
//
#include <hip/hip_runtime.h>
#include <hip/hip_bf16.h>
#include <stdint.h>

typedef __bf16 bf16;
typedef __bf16 bf16x8 __attribute__((ext_vector_type(8)));
typedef __bf16 bf16x4 __attribute__((ext_vector_type(4)));
typedef float f32x4 __attribute__((ext_vector_type(4)));

#define KDIM 768
#define NHEAD 12
#define HDIM 64
#define NTOK 1024
#define BATCH 8

// XOR swizzle for row-major [row][128B-row] LDS tiles (attention)
#define SWZ(row, b) ((b) ^ (((row) & 7) << 4))

__device__ __forceinline__ void gl_lds16(const bf16* g, bf16* l) {
    __builtin_amdgcn_global_load_lds((const __attribute__((address_space(1))) void*)g,
                                     (__attribute__((address_space(3))) void*)l, 16, 0, 0);
}

// ---------------- fp32 -> bf16 convert (all three tensors, one launch) ----------------
__global__ void k_cvt_all(const float* __restrict__ x, const float* __restrict__ wq,
                          const float* __restrict__ wp, bf16* __restrict__ xb,
                          bf16* __restrict__ wqb, bf16* __restrict__ wpb) {
    int b = blockIdx.x;
    const float* src;
    bf16* dst;
    int base;
    if (b < 6144)       { src = x;  dst = xb;  base = b; }
    else if (b < 7872)  { src = wq; dst = wqb; base = b - 6144; }
    else                { src = wp; dst = wpb; base = b - 7872; }
    int i = (base * 256 + threadIdx.x) * 4;
    float4 v = *(const float4*)(src + i);
    bf16x4 o;
    o[0] = (bf16)v.x; o[1] = (bf16)v.y; o[2] = (bf16)v.z; o[3] = (bf16)v.w;
    *(bf16x4*)(dst + i) = o;
}

// =====================================================================================
// GEMM: 128(M) x 192(N) x K, BK=32, 4 waves (2x2 -> per-wave 64x96, acc[4][6]).
// LDS: 3-slot ring (A 8KB + B 12KB per slot = 60KB total) -> 2 blocks/CU.
// Tile kt computes slot kt%3 while staging kt+2 into (kt+2)%3; end-of-tile
// s_waitcnt vmcnt(5) drains ONLY tile kt+1's 5 loads (counted, never 0 in-loop).
// Writes during kt go to slot (kt+2)%3, which is read neither at kt nor kt+1 ->
// ONE s_barrier per K-tile. LDS rows are 64B (one row's K=32); 16B chunk at
// pos = c ^ ((row>>1)&3) -> 16-lane frag reads cover all 8 bank-slots 2x (free).
// gl_lds writes lane-linear, so the global SOURCE k-chunk is pre-permuted the same way.
// =====================================================================================

#define G_MFMA(a, b, c) __builtin_amdgcn_mfma_f32_16x16x32_bf16(a, b, c, 0, 0, 0)
#define NT3 24  // 768 / 32

#define TILE_ITER(SC, SS, kt) do {                                               \
    const char* Ab8 = (const char*)sA[SC];                                       \
    const char* Bb8 = (const char*)sB[SC];                                       \
    bf16x8 af[4];                                                                \
    _Pragma("unroll")                                                            \
    for (int m = 0; m < 4; ++m)                                                  \
        af[m] = *(const bf16x8*)(Ab8 + (wr * 64 + m * 16 + lr) * 64 + kxoff);    \
    bf16x8 bfr[3];                                                               \
    _Pragma("unroll")                                                            \
    for (int n = 0; n < 3; ++n)                                                  \
        bfr[n] = *(const bf16x8*)(Bb8 + (wc * 96 + n * 16 + lr) * 64 + kxoff);   \
    if ((kt) < NT3 - 2) {                                                        \
        int k2 = ((kt) + 2) * 32;                                                \
        gl_lds16(Ab + (size_t)srow * KDIM + k2 + spos,        &sA[SS][t * 8]);         \
        gl_lds16(Ab + (size_t)(64 + srow) * KDIM + k2 + spos, &sA[SS][t * 8 + 2048]);  \
        gl_lds16(Wb + (size_t)srow * KDIM + k2 + spos,        &sB[SS][t * 8]);         \
    }                                                                            \
    __builtin_amdgcn_s_setprio(1);                                               \
    _Pragma("unroll")                                                            \
    for (int m = 0; m < 4; ++m)                                                  \
        _Pragma("unroll")                                                        \
        for (int n = 0; n < 3; ++n)                                              \
            acc[m][n] = G_MFMA(af[m], bfr[n], acc[m][n]);                        \
    __builtin_amdgcn_s_setprio(0);                                               \
    _Pragma("unroll")                                                            \
    for (int n = 0; n < 3; ++n)                                                  \
        bfr[n] = *(const bf16x8*)(Bb8 + (wc * 96 + (n + 3) * 16 + lr) * 64 + kxoff); \
    if ((kt) < NT3 - 2) {                                                        \
        int k2 = ((kt) + 2) * 32;                                                \
        gl_lds16(Wb + (size_t)(64 + srow) * KDIM + k2 + spos,  &sB[SS][t * 8 + 2048]); \
        gl_lds16(Wb + (size_t)(128 + srow) * KDIM + k2 + spos, &sB[SS][t * 8 + 4096]); \
    }                                                                            \
    __builtin_amdgcn_s_setprio(1);                                               \
    _Pragma("unroll")                                                            \
    for (int m = 0; m < 4; ++m)                                                  \
        _Pragma("unroll")                                                        \
        for (int n = 0; n < 3; ++n)                                              \
            acc[m][n + 3] = G_MFMA(af[m], bfr[n], acc[m][n + 3]);                \
    __builtin_amdgcn_s_setprio(0);                                               \
    if ((kt) < NT3 - 2)       { asm volatile("s_waitcnt vmcnt(5)" ::: "memory"); } \
    else if ((kt) == NT3 - 2) { asm volatile("s_waitcnt vmcnt(0)" ::: "memory"); } \
    asm volatile("s_barrier" ::: "memory");                                      \
} while (0)

#define GEMM_BODY(A_PTR, W_PTR)                                                  \
    const int t = threadIdx.x;                                                   \
    const int lane = t & 63;                                                     \
    const int wv = t >> 6;                  /* 0..3 */                           \
    const int wr = wv >> 1, wc = wv & 1;    /* 2 x 2 wave grid */                \
    const int lr = lane & 15, lg = lane >> 4;                                    \
    const int kxoff = (lg << 4) ^ (((lr >> 1) & 3) << 4);                        \
    const int srow = t >> 2;                /* staged row 0..63 */               \
    const int spos = (((t & 3) ^ ((t >> 3) & 3))) * 8; /* pre-swizzled src */    \
    const int bm = blockIdx.x, bn = blockIdx.y;                                  \
    const bf16* Ab = (A_PTR) + (size_t)bm * 128 * KDIM;                          \
    const bf16* Wb = (W_PTR) + (size_t)bn * 192 * KDIM;                          \
    f32x4 acc[4][6] = {};                                                        \
    /* prologue: stage tiles 0,1 into slots 0,1 */                               \
    gl_lds16(Ab + (size_t)srow * KDIM + spos,              &sA[0][t * 8]);       \
    gl_lds16(Ab + (size_t)(64 + srow) * KDIM + spos,       &sA[0][t * 8 + 2048]);\
    gl_lds16(Wb + (size_t)srow * KDIM + spos,              &sB[0][t * 8]);       \
    gl_lds16(Wb + (size_t)(64 + srow) * KDIM + spos,       &sB[0][t * 8 + 2048]);\
    gl_lds16(Wb + (size_t)(128 + srow) * KDIM + spos,      &sB[0][t * 8 + 4096]);\
    gl_lds16(Ab + (size_t)srow * KDIM + 32 + spos,         &sA[1][t * 8]);       \
    gl_lds16(Ab + (size_t)(64 + srow) * KDIM + 32 + spos,  &sA[1][t * 8 + 2048]);\
    gl_lds16(Wb + (size_t)srow * KDIM + 32 + spos,         &sB[1][t * 8]);       \
    gl_lds16(Wb + (size_t)(64 + srow) * KDIM + 32 + spos,  &sB[1][t * 8 + 2048]);\
    gl_lds16(Wb + (size_t)(128 + srow) * KDIM + 32 + spos, &sB[1][t * 8 + 4096]);\
    asm volatile("s_waitcnt vmcnt(5)" ::: "memory");                             \
    asm volatile("s_barrier" ::: "memory");                                      \
    _Pragma("unroll 1")                                                          \
    for (int g = 0; g < 8; ++g) {                                                \
        TILE_ITER(0, 2, g * 3);                                                  \
        TILE_ITER(1, 0, g * 3 + 1);                                              \
        TILE_ITER(2, 1, g * 3 + 2);                                              \
    }

__global__ __launch_bounds__(256, 2) void k_gemm_qkv(
    const bf16* __restrict__ A, const bf16* __restrict__ W,
    bf16* __restrict__ qb, bf16* __restrict__ kb, bf16* __restrict__ vb)
{
    __shared__ __attribute__((aligned(16))) bf16 sA[3][4096];   // 128 rows x 32
    __shared__ __attribute__((aligned(16))) bf16 sB[3][6144];   // 192 rows x 32
    GEMM_BODY(A, W);

    const float QSC = 0.18033688011112042f;  // 0.125 * log2(e) folded into q
#pragma unroll
    for (int n = 0; n < 6; ++n) {
        int o = bn * 192 + wc * 96 + n * 16 + lr;
        int s = o / 768;
        int rem = o - s * 768;
        int head = rem >> 6;
        int d = o & 63;
        bf16* dst = (s == 0) ? qb : ((s == 1) ? kb : vb);
        float sc = (s == 0) ? QSC : 1.0f;
#pragma unroll
        for (int m = 0; m < 4; ++m) {
            int grow = bm * 128 + wr * 64 + m * 16 + lg * 4;
            int bidx = grow >> 10;
            int tok = grow & 1023;
            size_t base = (((size_t)bidx * NHEAD + head) * NTOK + tok) * HDIM + d;
#pragma unroll
            for (int r = 0; r < 4; ++r)
                dst[base + (size_t)r * HDIM] = (bf16)(acc[m][n][r] * sc);
        }
    }
}

__global__ __launch_bounds__(256, 2) void k_gemm_proj(
    const bf16* __restrict__ A, const bf16* __restrict__ W,
    const float* __restrict__ bias, float* __restrict__ out)
{
    __shared__ __attribute__((aligned(16))) bf16 sA[3][4096];
    __shared__ __attribute__((aligned(16))) bf16 sB[3][6144];
    GEMM_BODY(A, W);

#pragma unroll
    for (int n = 0; n < 6; ++n) {
        int col = bn * 192 + wc * 96 + n * 16 + lr;
        float bv = bias[col];
#pragma unroll
        for (int m = 0; m < 4; ++m) {
            int grow = bm * 128 + wr * 64 + m * 16 + lg * 4;
#pragma unroll
            for (int r = 0; r < 4; ++r)
                out[(size_t)(grow + r) * KDIM + col] = acc[m][n][r] + bv;
        }
    }
}

// ---------------- banded flash attention (unchanged from round 4) ----------------
__global__ __launch_bounds__(256) void k_attn(
    const bf16* __restrict__ qbuf, const bf16* __restrict__ kbuf,
    const bf16* __restrict__ vbuf, bf16* __restrict__ ob)
{
    const int x = blockIdx.x;
    const int sub = x >> 3;
    const int bh = (x & 7) * 12 + (sub >> 4);   // 12 bh per XCD
    const int qblk = sub & 15;                   // == h_q
    const int head = bh % NHEAD, bidx = bh / NHEAD;
    const bf16* Q  = qbuf + (size_t)bh * NTOK * HDIM;
    const bf16* Kp = kbuf + (size_t)bh * NTOK * HDIM;
    const bf16* Vp = vbuf + (size_t)bh * NTOK * HDIM;

    const int t = threadIdx.x, lane = t & 63, wv = t >> 6;
    const int lr = lane & 15, lg = lane >> 4, lkb = lg * 8;

    __shared__ bf16 Ks[2][64 * 64];   // [key][d], swizzled
    __shared__ bf16 vT[2][64 * 64];   // [d][key], swizzled
    __shared__ bf16 pls[4][16 * 64];  // per-wave P [q][key], swizzled

    {
        bf16x8 z = {};
        *(bf16x8*)&pls[wv][lane * 16] = z;
        *(bf16x8*)&pls[wv][lane * 16 + 8] = z;
    }

    bf16x8 qf[2];
#pragma unroll
    for (int ks = 0; ks < 2; ++ks)
        qf[ks] = *(const bf16x8*)(Q + (size_t)(qblk * 64 + wv * 16 + lr) * HDIM + ks * 32 + lkb);

    f32x4 acc[4] = {};
    float mrow[4] = {-1e30f, -1e30f, -1e30f, -1e30f};
    float lrow[4] = {0.f, 0.f, 0.f, 0.f};

    const int kh0 = (qblk - 3 < 0) ? 0 : qblk - 3;
    const int kh1 = (qblk + 3 > 15) ? 15 : qblk + 3;

    const int sj = t >> 2;
    const int sd = (t & 3) * 16;

    const bf16* ks0 = Kp + (size_t)(kh0 * 64 + sj) * HDIM + sd;
    const bf16* vs0 = Vp + (size_t)(kh0 * 64 + sj) * HDIM + sd;
    bf16x8 gk0 = *(const bf16x8*)ks0, gk1 = *(const bf16x8*)(ks0 + 8);
    bf16x8 gv0 = *(const bf16x8*)vs0, gv1 = *(const bf16x8*)(vs0 + 8);

    char* pb8 = (char*)pls[wv];
    const int wq0 = wv * 16 + lg * 4;
    int cur = 0;

    for (int kh = kh0; kh <= kh1; ++kh) {
        char* kb8 = (char*)Ks[cur];
        char* vb8 = (char*)vT[cur];
        {
            int kbo = sj * 128 + sd * 2;
            *(bf16x8*)(kb8 + SWZ(sj, kbo)) = gk0;
            *(bf16x8*)(kb8 + SWZ(sj, kbo + 16)) = gk1;
        }
#pragma unroll
        for (int ii = 0; ii < 8; ++ii) {
            int d = sd + ii;
            *(bf16*)(vb8 + SWZ(d, (d << 7) + (sj << 1))) = gv0[ii];
        }
#pragma unroll
        for (int ii = 0; ii < 8; ++ii) {
            int d = sd + 8 + ii;
            *(bf16*)(vb8 + SWZ(d, (d << 7) + (sj << 1))) = gv1[ii];
        }
        if (kh < kh1) {
            const bf16* kn = Kp + (size_t)((kh + 1) * 64 + sj) * HDIM + sd;
            const bf16* vn = Vp + (size_t)((kh + 1) * 64 + sj) * HDIM + sd;
            gk0 = *(const bf16x8*)kn; gk1 = *(const bf16x8*)(kn + 8);
            gv0 = *(const bf16x8*)vn; gv1 = *(const bf16x8*)(vn + 8);
        }
        asm volatile("s_waitcnt lgkmcnt(0)" ::: "memory");
        __builtin_amdgcn_s_barrier();

        f32x4 s[3];
#pragma unroll
        for (int jj = 0; jj < 3; ++jj) {
            int j = wv - 1 + jj;
            if (j >= 0 && j <= 3) {
                int key = j * 16 + lr;
                int kbase = key * 128;
                bf16x8 kf0 = *(const bf16x8*)(kb8 + SWZ(key, kbase + lg * 16));
                bf16x8 kf1 = *(const bf16x8*)(kb8 + SWZ(key, kbase + 64 + lg * 16));
                f32x4 sv = {};
                sv = __builtin_amdgcn_mfma_f32_16x16x32_bf16(qf[0], kf0, sv, 0, 0, 0);
                sv = __builtin_amdgcn_mfma_f32_16x16x32_bf16(qf[1], kf1, sv, 0, 0, 0);
#pragma unroll
                for (int r = 0; r < 4; ++r) {
                    int dw = wq0 + r - key;
                    sv[r] = (dw >= -5 && dw <= 5) ? sv[r] : -1e30f;
                }
                s[jj] = sv;
            } else {
                s[jj] = f32x4{-1e30f, -1e30f, -1e30f, -1e30f};
            }
        }

        float pm[4], scl[4];
#pragma unroll
        for (int r = 0; r < 4; ++r) pm[r] = fmaxf(fmaxf(s[0][r], s[1][r]), s[2][r]);
#pragma unroll
        for (int off = 1; off < 16; off <<= 1)
#pragma unroll
            for (int r = 0; r < 4; ++r) pm[r] = fmaxf(pm[r], __shfl_xor(pm[r], off));
#pragma unroll
        for (int r = 0; r < 4; ++r) {
            float mn = fmaxf(mrow[r], pm[r]);
            scl[r] = exp2f(mrow[r] - mn);
            mrow[r] = mn;
        }
#pragma unroll
        for (int dt = 0; dt < 4; ++dt)
#pragma unroll
            for (int r = 0; r < 4; ++r) acc[dt][r] *= scl[r];

        float psum[4] = {0.f, 0.f, 0.f, 0.f};
#pragma unroll
        for (int jj = 0; jj < 3; ++jj) {
            int j = wv - 1 + jj;
            if (j >= 0 && j <= 3) {
#pragma unroll
                for (int r = 0; r < 4; ++r) {
                    float p = exp2f(s[jj][r] - mrow[r]);
                    psum[r] += p;
                    int row = lg * 4 + r;
                    *(bf16*)(pb8 + SWZ(row, row * 128 + (j * 16 + lr) * 2)) = (bf16)p;
                }
            }
        }
#pragma unroll
        for (int r = 0; r < 4; ++r) lrow[r] = lrow[r] * scl[r] + psum[r];

        bf16x8 pf0 = *(const bf16x8*)(pb8 + SWZ(lr, lr * 128 + lg * 16));
        bf16x8 pf1 = *(const bf16x8*)(pb8 + SWZ(lr, lr * 128 + 64 + lg * 16));
#pragma unroll
        for (int dt = 0; dt < 4; ++dt) {
            int vrow = dt * 16 + lr;
            bf16x8 vf0 = *(const bf16x8*)(vb8 + SWZ(vrow, vrow * 128 + lg * 16));
            bf16x8 vf1 = *(const bf16x8*)(vb8 + SWZ(vrow, vrow * 128 + 64 + lg * 16));
            acc[dt] = __builtin_amdgcn_mfma_f32_16x16x32_bf16(pf0, vf0, acc[dt], 0, 0, 0);
            acc[dt] = __builtin_amdgcn_mfma_f32_16x16x32_bf16(pf1, vf1, acc[dt], 0, 0, 0);
        }
        cur ^= 1;
    } // kh

#pragma unroll
    for (int off = 1; off < 16; off <<= 1)
#pragma unroll
        for (int r = 0; r < 4; ++r) lrow[r] += __shfl_xor(lrow[r], off);

#pragma unroll
    for (int r = 0; r < 4; ++r) {
        float inv = 1.0f / lrow[r];
        int tok = qblk * 64 + wv * 16 + lg * 4 + r;
        size_t rowbase = ((size_t)bidx * NTOK + tok) * KDIM + head * HDIM;
#pragma unroll
        for (int dt = 0; dt < 4; ++dt)
            ob[rowbase + dt * 16 + lr] = (bf16)(acc[dt][r] * inv);
    }
}

// ---------------- launcher ----------------
extern "C" void kernel_launch(void* const* d_in, const int* in_sizes, int n_in,
                              void* d_out, int out_size, void* d_ws, size_t ws_size,
                              hipStream_t stream) {
    const float* x      = (const float*)d_in[0];
    const float* w_qkv  = (const float*)d_in[1];
    const float* w_proj = (const float*)d_in[2];
    const float* b_proj = (const float*)d_in[3];
    float* out = (float*)d_out;

    char* ws = (char*)d_ws;
    bf16* xb  = (bf16*)(ws);                  // 8192*768*2   = 12582912
    bf16* wqb = (bf16*)(ws + 12582912);       // 2304*768*2   =  3538944
    bf16* wpb = (bf16*)(ws + 16121856);       // 768*768*2    =  1179648
    bf16* qb  = (bf16*)(ws + 17301504);       // 96*1024*64*2 = 12582912
    bf16* kb  = (bf16*)(ws + 29884416);
    bf16* vb  = (bf16*)(ws + 42467328);
    bf16* aob = (bf16*)(ws + 55050240);       // attn out bf16 [8192][768]

    hipLaunchKernelGGL(k_cvt_all, dim3(8448), dim3(256), 0, stream, x, w_qkv, w_proj, xb, wqb, wpb);
    hipLaunchKernelGGL(k_gemm_qkv, dim3(64, 12), dim3(256), 0, stream, xb, wqb, qb, kb, vb);
    hipLaunchKernelGGL(k_attn,     dim3(1536), dim3(256), 0, stream, qb, kb, vb, aob);
    hipLaunchKernelGGL(k_gemm_proj, dim3(64, 4), dim3(256), 0, stream, aob, wpb, b_proj, out);
}